// Round 11
// baseline (582.555 us; speedup 1.0000x reference)
//
#include <hip/hip_runtime.h>
#include <hip/hip_bf16.h>
#include <stdint.h>

typedef unsigned int u32;
typedef unsigned long long u64;
typedef unsigned char u8;
typedef unsigned short u16;

// ---------------------------------------------------------------------------
// Reduction order for n[v] = sum_f image[v,f]^2 bit-matches the XLA:CPU
// reference (H1 tree; vectorized form verified bit-exact, PASS R8/R9).
// ---------------------------------------------------------------------------

// ---- K1: per-vertex squared norm (2 lanes/vertex, float4 loads) ----
__global__ __launch_bounds__(256) void vnorm_kernel(const float* __restrict__ image,
                                                    float* __restrict__ nrm, int V) {
#pragma clang fp contract(off)
  int t = blockIdx.x * 256 + threadIdx.x;
  int v = t >> 1, h = t & 1;
  if (v >= V) return;
  const float4* r4 = (const float4*)(image + (size_t)v * 128) + h;
  float4 a, x;
  x = r4[0];
  a.x = x.x * x.x; a.y = x.y * x.y; a.z = x.z * x.z; a.w = x.w * x.w;
#pragma unroll
  for (int i = 1; i < 16; ++i) {
    x = r4[i * 2];
    a.x = a.x + x.x * x.x; a.y = a.y + x.y * x.y;
    a.z = a.z + x.z * x.z; a.w = a.w + x.w * x.w;
  }
  float bx = __shfl_xor(a.x, 1), by = __shfl_xor(a.y, 1);
  float bz = __shfl_xor(a.z, 1), bw = __shfl_xor(a.w, 1);
  a.x = a.x + bx; a.y = a.y + by; a.z = a.z + bz; a.w = a.w + bw;
  float r0 = a.x + a.z;
  float r1 = a.y + a.w;
  float s = r0 + r1;
  if (h == 0) nrm[v] = s;
}

// ---- K2: per-edge priority, key, boundary + global min/max ----
__global__ __launch_bounds__(256) void edge_kernel(const float* __restrict__ nrm,
                                                   const float* __restrict__ vs,
                                                   const int* __restrict__ edges,
                                                   u64* __restrict__ keysA,
                                                   u8* __restrict__ bnd,
                                                   float* __restrict__ out_sq,
                                                   u32* __restrict__ gmm, int E) {
#pragma clang fp contract(off)
  __shared__ u32 smn[4], smx[4];
  int tid = threadIdx.x;
  int e = blockIdx.x * 256 + tid;
  u32 mn = 0xFFFFFFFFu, mx = 0u;
  if (e < E) {
    int v0 = edges[e], v1 = edges[E + e];
    float sq = nrm[v0] + nrm[v1];
    out_sq[e] = sq;
    u32 sb = __float_as_uint(sq);
    keysA[e] = ((u64)sb << 32) | (u32)e;
    float ax = vs[2 * v0], ay = vs[2 * v0 + 1];
    float bx = vs[2 * v1], by = vs[2 * v1 + 1];
    const float lo = 0.01f, hi = 0.99f;
    bool b = (ax < lo) | (ax > hi) | (ay < lo) | (ay > hi)
           | (bx < lo) | (bx > hi) | (by < lo) | (by > hi);
    bnd[e] = b ? 1 : 0;
    mn = sb; mx = sb;
  }
  int lane = tid & 63, wv = tid >> 6;
#pragma unroll
  for (int d = 32; d >= 1; d >>= 1) {
    u32 a = __shfl_xor(mn, d); mn = (a < mn) ? a : mn;
    u32 b2 = __shfl_xor(mx, d); mx = (b2 > mx) ? b2 : mx;
  }
  if (lane == 0) { smn[wv] = mn; smx[wv] = mx; }
  __syncthreads();
  if (tid == 0) {
    u32 m = smn[0], M = smx[0];
#pragma unroll
    for (int w = 1; w < 4; ++w) {
      if (smn[w] < m) m = smn[w];
      if (smx[w] > M) M = smx[w];
    }
    atomicMin(&gmm[0], m);
    atomicMax(&gmm[1], M);
  }
}

__device__ inline u32 bucket_of(u32 sb, u32 minv, u32 range) {
  return (u32)(((u64)(sb - minv) << 14) / ((u64)range + 1ull));   // 16384 buckets
}

// ---- K3: bucket histogram ----
__global__ __launch_bounds__(256) void hist_kernel(const u64* __restrict__ keysA,
                                                   const u32* __restrict__ gmm,
                                                   u32* __restrict__ ghist, int E) {
  int e = blockIdx.x * 256 + threadIdx.x;
  if (e >= E) return;
  u32 minv = gmm[0], range = gmm[1] - minv;
  u32 b = bucket_of((u32)(keysA[e] >> 32), minv, range);
  atomicAdd(&ghist[b], 1u);
}

// ---- K4: scan of 16384 bucket counts ----
__global__ __launch_bounds__(1024) void scan16k_kernel(const u32* __restrict__ ghist,
                                                       u32* __restrict__ starts,
                                                       u32* __restrict__ cursor, int E) {
  __shared__ u32 wsum[16];
  int tid = threadIdx.x;
  int lane = tid & 63, wv = tid >> 6;
  u32 loc[16];
  u32 s = 0;
#pragma unroll
  for (int i = 0; i < 16; ++i) { loc[i] = ghist[tid * 16 + i]; s += loc[i]; }
  u32 inc = s;
#pragma unroll
  for (int d = 1; d < 64; d <<= 1) {
    u32 t = __shfl_up(inc, d);
    if (lane >= d) inc += t;
  }
  if (lane == 63) wsum[wv] = inc;
  __syncthreads();
  if (tid == 0) {
    u32 r = 0;
#pragma unroll
    for (int w = 0; w < 16; ++w) { u32 t = wsum[w]; wsum[w] = r; r += t; }
  }
  __syncthreads();
  u32 run = wsum[wv] + (inc - s);
#pragma unroll
  for (int i = 0; i < 16; ++i) {
    starts[tid * 16 + i] = run;
    cursor[tid * 16 + i] = run;
    run += loc[i];
  }
  if (tid == 0) starts[16384] = (u32)E;
}

// ---- K5: scatter keys into bucket slots ----
__global__ __launch_bounds__(256) void scatter_kernel(const u64* __restrict__ keysA,
                                                      const u32* __restrict__ gmm,
                                                      u32* __restrict__ cursor,
                                                      u64* __restrict__ keysB, int E) {
  int e = blockIdx.x * 256 + threadIdx.x;
  if (e >= E) return;
  u64 key = keysA[e];
  u32 minv = gmm[0], range = gmm[1] - minv;
  u32 b = bucket_of((u32)(key >> 32), minv, range);
  u32 pos = atomicAdd(&cursor[b], 1u);
  keysB[pos] = key;
}

// ---- K6: per-bucket 128-elem bitonic sort (1 wave/bucket) + pack write ----
__global__ __launch_bounds__(256) void bucketsort_kernel(const u64* __restrict__ keysB,
                                                         const u32* __restrict__ starts,
                                                         const int* __restrict__ edges,
                                                         const u8* __restrict__ bnd,
                                                         u64* __restrict__ pack,
                                                         int E, int V, int Npad) {
  int tid = threadIdx.x;
  int lane = tid & 63;
  int w = blockIdx.x * 4 + (tid >> 6);           // bucket id
  u32 start = starts[w];
  int cnt = (int)(starts[w + 1] - start);
  if (cnt > 128) cnt = 128;                      // safety clamp (P ~ 0)
  u64 k0 = (lane < cnt) ? keysB[start + lane] : ~0ull;
  u64 k1 = (64 + lane < cnt) ? keysB[start + 64 + lane] : ~0ull;
  int idx0 = lane * 2, idx1 = lane * 2 + 1;
#pragma unroll
  for (int k = 2; k <= 128; k <<= 1) {
#pragma unroll
    for (int j = 64; j >= 1; j >>= 1) {
      if (j > k / 2) continue;
      if (j >= 2) {
        int lj = j >> 1;
        u64 p0 = __shfl_xor(k0, lj);
        u64 p1 = __shfl_xor(k1, lj);
        bool keepMin0 = (((idx0 & j) == 0) == ((idx0 & k) == 0));
        k0 = keepMin0 ? (k0 < p0 ? k0 : p0) : (k0 > p0 ? k0 : p0);
        k1 = keepMin0 ? (k1 < p1 ? k1 : p1) : (k1 > p1 ? k1 : p1);
      } else {
        bool up = ((idx0 & k) == 0);
        u64 mn = (k0 < k1) ? k0 : k1;
        u64 mx = (k0 < k1) ? k1 : k0;
        k0 = up ? mn : mx;
        k1 = up ? mx : mn;
      }
    }
  }
  if (idx0 < cnt) {
    u32 id = (u32)k0;
    int vv0 = edges[id], vv1 = edges[E + id];
    pack[start + idx0] = (u64)(u32)(vv0 | (vv1 << 16)) | ((u64)bnd[id] << 32);
  }
  if (idx1 < cnt) {
    u32 id = (u32)k1;
    int vv0 = edges[id], vv1 = edges[E + id];
    pack[start + idx1] = (u64)(u32)(vv0 | (vv1 << 16)) | ((u64)bnd[id] << 32);
  }
  // sentinel tail [E, Npad): nb=1 (never kills), verts in [V, V+512)
  int g = blockIdx.x * 256 + tid;
  int i = E + g;
  if (i < Npad) {
    u32 sv0 = (u32)V + (((u32)i & 255u) << 1);
    pack[i] = (u64)(sv0 | ((sv0 + 1) << 16)) | (1ull << 32);
  }
}

// ---- K7: exact greedy collapse via guaranteed-progress peel ---------------
// Edge statuses UNDECIDED/KILL/NOKILL; decisions permanent (no oscillation).
// tUK[v] = min over undecided|kill edges targeting v of (ord<<1)|isUndecided.
// Round: (A) rebuild tUK; (B) undecided e:
//   earlier KILL targets v0 or v1          -> NOKILL (endpoint died first)
//   no earlier und/kill at v0, e min at v1 -> KILL
//   else wait. Earliest undecided edge always decides => progress each round.
// Threshold post-hoc: first `needed` kills in order == bounded-run kills.
#define SEG 30720
#define SEGJ 30
#define SEGW 960

__device__ inline void lds_min_u16(u16* tarr, int idx, u16 val) {
  u32* w = (u32*)(tarr + (idx & ~1));
  int sh = (idx & 1) * 16;
  u32 old = *w;
  while (true) {
    u32 cur = (old >> sh) & 0xffffu;
    if ((u32)val >= cur) break;
    u32 nv = (old & ~(0xffffu << sh)) | ((u32)val << sh);
    u32 prev = atomicCAS(w, old, nv);
    if (prev == old) break;
    old = prev;
  }
}

__global__ __launch_bounds__(1024) void peel_kernel(const u64* __restrict__ pack,
                                                    const int* __restrict__ tgt,
                                                    float* __restrict__ out,
                                                    u32* __restrict__ gbits,
                                                    int V, int E, int Npad) {
  __shared__ u16 tUK[50048];
  __shared__ u32 alive[1600];
  __shared__ u32 undw[SEGW];
  __shared__ u32 killw[SEGW];
  __shared__ u32 wsum[17];
  __shared__ u32 misc[2];
  int tid = threadIdx.x;
  int lane = tid & 63, wvi = tid >> 6;
  for (int i = tid; i < 1600; i += 1024) alive[i] = 0xFFFFFFFFu;
  int target = tgt[0];
  int needed = V - target; if (needed < 0) needed = 0;
  int applied = 0;
  __syncthreads();
  for (int segbase = 0; segbase < E && applied < needed; segbase += SEG) {
    // ---- init statuses (one ballot per wave per j) ----
    for (int j = 0; j < SEGJ; ++j) {
      int el = j * 1024 + tid;
      int e = segbase + el;
      int und = 0;
      if (e < Npad) {
        u64 pk = pack[e];
        int v0 = (int)(pk & 0xffff), v1 = (int)((pk >> 16) & 0xffff);
        int nb = (int)((pk >> 32) & 1);
        if (!nb) {
          int a0 = (int)((alive[v0 >> 5] >> (v0 & 31)) & 1);
          int a1 = (int)((alive[v1 >> 5] >> (v1 & 31)) & 1);
          und = a0 & a1;
        }
      }
      u64 bb = __ballot(und);
      int wA = j * 32 + wvi * 2;
      if (lane == 0)  { undw[wA] = (u32)bb; killw[wA] = 0u; }
      if (lane == 32) { undw[wA + 1] = (u32)(bb >> 32); killw[wA + 1] = 0u; }
    }
    __syncthreads();
    // ---- peel rounds (hard cap: no hang possible) ----
    for (int round = 0; round < 1500; ++round) {
      // phase A: rebuild tUK from undecided|kill edges
      for (int i = tid; i < 25024; i += 1024) ((u32*)tUK)[i] = 0xFFFFFFFFu;
      if (tid < 2) misc[tid] = 0u;
      __syncthreads();
      for (int j = 0; j < SEGJ; ++j) {
        u32 uw = undw[j * 32 + (tid >> 5)];
        u32 kw = killw[j * 32 + (tid >> 5)];
        int bit = tid & 31;
        int u = (int)((uw >> bit) & 1), k = (int)((kw >> bit) & 1);
        if (u | k) {
          int el = j * 1024 + tid;
          u64 pk = pack[segbase + el];
          int v1 = (int)((pk >> 16) & 0xffff);
          lds_min_u16(tUK, v1, (u16)(((u32)el << 1) | (u32)u));
        }
      }
      __syncthreads();
      // phase B: decisions from the stable snapshot
      for (int j = 0; j < SEGJ; ++j) {
        u32 uw = undw[j * 32 + (tid >> 5)];
        int bit = tid & 31;
        int u = (int)((uw >> bit) & 1);
        int dokill = 0, donk = 0;
        if (u) {
          int el = j * 1024 + tid;
          u64 pk = pack[segbase + el];
          int v0 = (int)(pk & 0xffff), v1 = (int)((pk >> 16) & 0xffff);
          u32 b0 = tUK[v0], b1 = tUK[v1];
          u32 myval = ((u32)el << 1) | 1u;
          donk = (int)(((b0 < myval) & ((b0 & 1u) ^ 1u)) |
                       ((b1 < myval) & ((b1 & 1u) ^ 1u)));
          int c0 = (v0 == v1) ? 1 : (int)(b0 > myval);
          int c1 = (int)(b1 == myval);
          dokill = c0 & c1 & (donk ^ 1);
        }
        u64 clr = __ballot(dokill | donk);
        u64 kil = __ballot(dokill);
        u64 rem = __ballot(u & ((dokill | donk) ^ 1));
        int wA = j * 32 + wvi * 2;
        if (lane == 0) {
          u32 cl = (u32)clr, kl = (u32)kil;
          if (cl) atomicAnd(&undw[wA], ~cl);
          if (kl) atomicOr(&killw[wA], kl);
          if (clr) atomicOr(&misc[0], 1u);
          if (rem) atomicOr(&misc[1], 1u);
        }
        if (lane == 32) {
          u32 ch = (u32)(clr >> 32), kh = (u32)(kil >> 32);
          if (ch) atomicAnd(&undw[wA + 1], ~ch);
          if (kh) atomicOr(&killw[wA + 1], kh);
        }
      }
      __syncthreads();
      u32 prog = misc[0], remv = misc[1];
      __syncthreads();                     // all reads done before next reset
      if (remv == 0u || prog == 0u) break;
    }
    // ---- rank kills by order, apply first `remaining` ----
    u32 kw0 = 0, lc = 0;
    if (tid < SEGW) { kw0 = killw[tid]; lc = (u32)__popc(kw0); }
    u32 inc = lc;
#pragma unroll
    for (int d = 1; d < 64; d <<= 1) {
      u32 t2 = __shfl_up(inc, d);
      if (lane >= d) inc += t2;
    }
    if (lane == 63) wsum[wvi] = inc;
    __syncthreads();
    if (tid == 0) {
      u32 r = 0;
#pragma unroll
      for (int w = 0; w < 16; ++w) { u32 t2 = wsum[w]; wsum[w] = r; r += t2; }
      wsum[16] = r;
    }
    __syncthreads();
    u32 ex = wsum[wvi] + (inc - lc);
    u32 totk = wsum[16];
    int remaining = needed - applied;
    if (tid < SEGW && kw0) {
      u32 m = kw0;
      while (m) {
        int p = __builtin_ctz(m);
        u32 rank = ex + (u32)__popc(kw0 & ((1u << p) - 1u)) + 1u;
        if (rank > (u32)remaining) break;
        u64 pk = pack[segbase + tid * 32 + p];
        int v1 = (int)((pk >> 16) & 0xffff);
        atomicAnd(&alive[v1 >> 5], ~(1u << (v1 & 31)));
        m &= m - 1;
      }
    }
    applied += (int)((totk < (u32)remaining) ? totk : (u32)remaining);
    __syncthreads();                       // applies visible before next segment
  }
  for (int i = tid; i < 1600; i += 1024) gbits[i] = alive[i];
  if (tid == 0) out[E + V] = (float)(V - applied);
}

// ---- K8: expand bit-mask to float outputs ----
__global__ __launch_bounds__(256) void expand_kernel(const u32* __restrict__ gbits,
                                                     float* __restrict__ out,
                                                     int V, int E) {
  int i = blockIdx.x * 256 + threadIdx.x;
  if (i < V) out[E + i] = ((gbits[i >> 5] >> (i & 31)) & 1) ? 1.0f : 0.0f;
}

extern "C" void kernel_launch(void* const* d_in, const int* in_sizes, int n_in,
                              void* d_out, int out_size, void* d_ws, size_t ws_size,
                              hipStream_t stream) {
  const float* image = (const float*)d_in[0];
  const float* vs    = (const float*)d_in[1];
  const int*   edges = (const int*)d_in[2];
  const int*   tgt   = (const int*)d_in[3];
  int V = in_sizes[1] / 2;                 // 50000
  int E = in_sizes[2] / 2;                 // 150000
  int Npad = ((E + 1023) / 1024) * 1024;   // 150528

  char* ws = (char*)d_ws;
  size_t o = 0;
  u64* keysA  = (u64*)(ws + o); o += (size_t)E * 8;
  u64* keysB  = (u64*)(ws + o); o += (size_t)E * 8;
  u64* pack   = (u64*)(ws + o); o += (size_t)Npad * 8;
  float* nrm  = (float*)(ws + o); o += (size_t)V * 4;
  u8*  bnd    = (u8*)(ws + o);  o += (size_t)E;
  o = (o + 255) & ~(size_t)255;
  u32* ghist  = (u32*)(ws + o); o += 16384 * 4;
  u32* starts = (u32*)(ws + o); o += 16385 * 4;
  u32* cursor = (u32*)(ws + o); o += 16384 * 4;
  u32* gbits  = (u32*)(ws + o); o += 6400;
  u32* gmm    = (u32*)(ws + o); o += 256;
  float* out = (float*)d_out;

  (void)hipMemsetAsync(ghist, 0, 16384 * 4, stream);
  (void)hipMemsetAsync(&gmm[0], 0xFF, 4, stream);   // min = 0xFFFFFFFF
  (void)hipMemsetAsync(&gmm[1], 0x00, 4, stream);   // max = 0

  int eb = (E + 255) / 256;
  vnorm_kernel<<<dim3((2 * V + 255) / 256), dim3(256), 0, stream>>>(image, nrm, V);
  edge_kernel<<<dim3(eb), dim3(256), 0, stream>>>(nrm, vs, edges, keysA, bnd, out, gmm, E);
  hist_kernel<<<dim3(eb), dim3(256), 0, stream>>>(keysA, gmm, ghist, E);
  scan16k_kernel<<<dim3(1), dim3(1024), 0, stream>>>(ghist, starts, cursor, E);
  scatter_kernel<<<dim3(eb), dim3(256), 0, stream>>>(keysA, gmm, cursor, keysB, E);
  bucketsort_kernel<<<dim3(4096), dim3(256), 0, stream>>>(keysB, starts, edges, bnd,
                                                          pack, E, V, Npad);
  peel_kernel<<<dim3(1), dim3(1024), 0, stream>>>(pack, tgt, out, gbits, V, E, Npad);
  expand_kernel<<<dim3((V + 255) / 256), dim3(256), 0, stream>>>(gbits, out, V, E);
}

// Round 12
// 260.971 us; speedup vs baseline: 2.2323x; 2.2323x over previous
//
#include <hip/hip_runtime.h>
#include <hip/hip_bf16.h>
#include <stdint.h>

typedef unsigned int u32;
typedef unsigned long long u64;
typedef unsigned char u8;
typedef unsigned short u16;

// ---------------------------------------------------------------------------
// Reduction order for n[v] = sum_f image[v,f]^2 bit-matches the XLA:CPU
// reference (H1 tree; vectorized form verified bit-exact, PASS R8/R9/R11).
// ---------------------------------------------------------------------------

// ---- K1: per-vertex squared norm (2 lanes/vertex, float4 loads) ----
__global__ __launch_bounds__(256) void vnorm_kernel(const float* __restrict__ image,
                                                    float* __restrict__ nrm, int V) {
#pragma clang fp contract(off)
  int t = blockIdx.x * 256 + threadIdx.x;
  int v = t >> 1, h = t & 1;
  if (v >= V) return;
  const float4* r4 = (const float4*)(image + (size_t)v * 128) + h;
  float4 a, x;
  x = r4[0];
  a.x = x.x * x.x; a.y = x.y * x.y; a.z = x.z * x.z; a.w = x.w * x.w;
#pragma unroll
  for (int i = 1; i < 16; ++i) {
    x = r4[i * 2];
    a.x = a.x + x.x * x.x; a.y = a.y + x.y * x.y;
    a.z = a.z + x.z * x.z; a.w = a.w + x.w * x.w;
  }
  float bx = __shfl_xor(a.x, 1), by = __shfl_xor(a.y, 1);
  float bz = __shfl_xor(a.z, 1), bw = __shfl_xor(a.w, 1);
  a.x = a.x + bx; a.y = a.y + by; a.z = a.z + bz; a.w = a.w + bw;
  float r0 = a.x + a.z;
  float r1 = a.y + a.w;
  float s = r0 + r1;
  if (h == 0) nrm[v] = s;
}

// ---- K2: per-edge priority, key, boundary + global min/max ----
__global__ __launch_bounds__(256) void edge_kernel(const float* __restrict__ nrm,
                                                   const float* __restrict__ vs,
                                                   const int* __restrict__ edges,
                                                   u64* __restrict__ keysA,
                                                   u8* __restrict__ bnd,
                                                   float* __restrict__ out_sq,
                                                   u32* __restrict__ gmm, int E) {
#pragma clang fp contract(off)
  __shared__ u32 smn[4], smx[4];
  int tid = threadIdx.x;
  int e = blockIdx.x * 256 + tid;
  u32 mn = 0xFFFFFFFFu, mx = 0u;
  if (e < E) {
    int v0 = edges[e], v1 = edges[E + e];
    float sq = nrm[v0] + nrm[v1];
    out_sq[e] = sq;
    u32 sb = __float_as_uint(sq);
    keysA[e] = ((u64)sb << 32) | (u32)e;
    float ax = vs[2 * v0], ay = vs[2 * v0 + 1];
    float bx = vs[2 * v1], by = vs[2 * v1 + 1];
    const float lo = 0.01f, hi = 0.99f;
    bool b = (ax < lo) | (ax > hi) | (ay < lo) | (ay > hi)
           | (bx < lo) | (bx > hi) | (by < lo) | (by > hi);
    bnd[e] = b ? 1 : 0;
    mn = sb; mx = sb;
  }
  int lane = tid & 63, wv = tid >> 6;
#pragma unroll
  for (int d = 32; d >= 1; d >>= 1) {
    u32 a = __shfl_xor(mn, d); mn = (a < mn) ? a : mn;
    u32 b2 = __shfl_xor(mx, d); mx = (b2 > mx) ? b2 : mx;
  }
  if (lane == 0) { smn[wv] = mn; smx[wv] = mx; }
  __syncthreads();
  if (tid == 0) {
    u32 m = smn[0], M = smx[0];
#pragma unroll
    for (int w = 1; w < 4; ++w) {
      if (smn[w] < m) m = smn[w];
      if (smx[w] > M) M = smx[w];
    }
    atomicMin(&gmm[0], m);
    atomicMax(&gmm[1], M);
  }
}

__device__ inline u32 bucket_of(u32 sb, u32 minv, u32 range) {
  return (u32)(((u64)(sb - minv) << 14) / ((u64)range + 1ull));   // 16384 buckets
}

// ---- K3: bucket histogram ----
__global__ __launch_bounds__(256) void hist_kernel(const u64* __restrict__ keysA,
                                                   const u32* __restrict__ gmm,
                                                   u32* __restrict__ ghist, int E) {
  int e = blockIdx.x * 256 + threadIdx.x;
  if (e >= E) return;
  u32 minv = gmm[0], range = gmm[1] - minv;
  u32 b = bucket_of((u32)(keysA[e] >> 32), minv, range);
  atomicAdd(&ghist[b], 1u);
}

// ---- K4: scan of 16384 bucket counts ----
__global__ __launch_bounds__(1024) void scan16k_kernel(const u32* __restrict__ ghist,
                                                       u32* __restrict__ starts,
                                                       u32* __restrict__ cursor, int E) {
  __shared__ u32 wsum[16];
  int tid = threadIdx.x;
  int lane = tid & 63, wv = tid >> 6;
  u32 loc[16];
  u32 s = 0;
#pragma unroll
  for (int i = 0; i < 16; ++i) { loc[i] = ghist[tid * 16 + i]; s += loc[i]; }
  u32 inc = s;
#pragma unroll
  for (int d = 1; d < 64; d <<= 1) {
    u32 t = __shfl_up(inc, d);
    if (lane >= d) inc += t;
  }
  if (lane == 63) wsum[wv] = inc;
  __syncthreads();
  if (tid == 0) {
    u32 r = 0;
#pragma unroll
    for (int w = 0; w < 16; ++w) { u32 t = wsum[w]; wsum[w] = r; r += t; }
  }
  __syncthreads();
  u32 run = wsum[wv] + (inc - s);
#pragma unroll
  for (int i = 0; i < 16; ++i) {
    starts[tid * 16 + i] = run;
    cursor[tid * 16 + i] = run;
    run += loc[i];
  }
  if (tid == 0) starts[16384] = (u32)E;
}

// ---- K5: scatter keys into bucket slots ----
__global__ __launch_bounds__(256) void scatter_kernel(const u64* __restrict__ keysA,
                                                      const u32* __restrict__ gmm,
                                                      u32* __restrict__ cursor,
                                                      u64* __restrict__ keysB, int E) {
  int e = blockIdx.x * 256 + threadIdx.x;
  if (e >= E) return;
  u64 key = keysA[e];
  u32 minv = gmm[0], range = gmm[1] - minv;
  u32 b = bucket_of((u32)(key >> 32), minv, range);
  u32 pos = atomicAdd(&cursor[b], 1u);
  keysB[pos] = key;
}

// ---- K6: per-bucket 128-elem bitonic sort (1 wave/bucket) + pack write ----
__global__ __launch_bounds__(256) void bucketsort_kernel(const u64* __restrict__ keysB,
                                                         const u32* __restrict__ starts,
                                                         const int* __restrict__ edges,
                                                         const u8* __restrict__ bnd,
                                                         u64* __restrict__ pack,
                                                         int E, int V, int Npad) {
  int tid = threadIdx.x;
  int lane = tid & 63;
  int w = blockIdx.x * 4 + (tid >> 6);           // bucket id
  u32 start = starts[w];
  int cnt = (int)(starts[w + 1] - start);
  if (cnt > 128) cnt = 128;                      // safety clamp (P ~ 0)
  u64 k0 = (lane < cnt) ? keysB[start + lane] : ~0ull;
  u64 k1 = (64 + lane < cnt) ? keysB[start + 64 + lane] : ~0ull;
  int idx0 = lane * 2, idx1 = lane * 2 + 1;
#pragma unroll
  for (int k = 2; k <= 128; k <<= 1) {
#pragma unroll
    for (int j = 64; j >= 1; j >>= 1) {
      if (j > k / 2) continue;
      if (j >= 2) {
        int lj = j >> 1;
        u64 p0 = __shfl_xor(k0, lj);
        u64 p1 = __shfl_xor(k1, lj);
        bool keepMin0 = (((idx0 & j) == 0) == ((idx0 & k) == 0));
        k0 = keepMin0 ? (k0 < p0 ? k0 : p0) : (k0 > p0 ? k0 : p0);
        k1 = keepMin0 ? (k1 < p1 ? k1 : p1) : (k1 > p1 ? k1 : p1);
      } else {
        bool up = ((idx0 & k) == 0);
        u64 mn = (k0 < k1) ? k0 : k1;
        u64 mx = (k0 < k1) ? k1 : k0;
        k0 = up ? mn : mx;
        k1 = up ? mx : mn;
      }
    }
  }
  if (idx0 < cnt) {
    u32 id = (u32)k0;
    int vv0 = edges[id], vv1 = edges[E + id];
    pack[start + idx0] = (u64)(u32)(vv0 | (vv1 << 16)) | ((u64)bnd[id] << 32);
  }
  if (idx1 < cnt) {
    u32 id = (u32)k1;
    int vv0 = edges[id], vv1 = edges[E + id];
    pack[start + idx1] = (u64)(u32)(vv0 | (vv1 << 16)) | ((u64)bnd[id] << 32);
  }
  // sentinel tail [E, Npad): nb=1 (never kills), verts in [V, V+512)
  int g = blockIdx.x * 256 + tid;
  int i = E + g;
  if (i < Npad) {
    u32 sv0 = (u32)V + (((u32)i & 255u) << 1);
    pack[i] = (u64)(sv0 | ((sv0 + 1) << 16)) | (1ull << 32);
  }
}

// ---- K7: exact greedy collapse, ordered 1024-edge batches + in-reg peel ---
// Batches processed sequentially (earlier batches fully decided & applied),
// so the peel runs only WITHIN a batch: 1 edge/thread in registers, expected
// chain depth ~2-4 rounds. Decision logic identical to R11's verified peel:
//   tUK[v] = min over und|kill batch edges targeting v of (pos<<1)|isUnd.
//   und e: earlier KILL at v0|v1 -> NOKILL; no earlier und|kill at v0 AND
//   min at v1 -> KILL; else wait. Earliest undecided always decides.
// Threshold post-hoc per batch: rank kills by pos, apply first `remaining`.
__device__ inline void lds_min_u16(u16* tarr, int idx, u16 val) {
  u32* w = (u32*)(tarr + (idx & ~1));
  int sh = (idx & 1) * 16;
  u32 old = *w;
  while (true) {
    u32 cur = (old >> sh) & 0xffffu;
    if ((u32)val >= cur) break;
    u32 nv = (old & ~(0xffffu << sh)) | ((u32)val << sh);
    u32 prev = atomicCAS(w, old, nv);
    if (prev == old) break;
    old = prev;
  }
}

__global__ __launch_bounds__(1024) void batch_kernel(const u64* __restrict__ pack,
                                                     const int* __restrict__ tgt,
                                                     float* __restrict__ out,
                                                     u32* __restrict__ gbits,
                                                     int V, int E, int Npad) {
  __shared__ u16 tUK[50560];     // 101 KB; covers sentinel verts < V+512
  __shared__ u32 alive[1600];
  __shared__ u32 wred[17];
  __shared__ u32 misc[4];
  int tid = threadIdx.x;
  int lane = tid & 63, wv = tid >> 6;
  for (int i = tid; i < 1600; i += 1024) alive[i] = 0xFFFFFFFFu;
  for (int i = tid; i < 25280; i += 1024) ((u32*)tUK)[i] = 0xFFFFFFFFu;
  if (tid < 4) misc[tid] = 0u;
  int target = tgt[0];
  int needed = V - target; if (needed < 0) needed = 0;
  int remaining = needed;
  __syncthreads();
  int nbatch = Npad / 1024;
  u64 pk = pack[tid];
  for (int b = 0; b < nbatch; ++b) {
    if (remaining <= 0) break;
    u64 pkn = (b + 1 < nbatch) ? pack[(b + 1) * 1024 + tid] : pk;
    int v0 = (int)(pk & 0xffff), v1 = (int)((pk >> 16) & 0xffff);
    int nb = (int)((pk >> 32) & 1);
    int a0 = (int)((alive[v0 >> 5] >> (v0 & 31)) & 1);
    int a1 = (int)((alive[v1 >> 5] >> (v1 & 31)) & 1);
    int und = a0 & a1 & (nb ^ 1);
    int kill = 0;
    u32 myval = ((u32)tid << 1) | 1u;
    for (int r = 0; r < 1100; ++r) {
      if (und | kill) lds_min_u16(tUK, v1, (u16)(((u32)tid << 1) | (u32)und));
      __syncthreads();                                   // B1: posts visible
      int newk = 0, newnk = 0;
      if (und) {
        u32 b0v = (v0 == v1) ? 0xFFFFu : (u32)tUK[v0];
        u32 b1v = (u32)tUK[v1];
        int ek = (int)(((b0v < myval) & ((b0v & 1u) ^ 1u)) |
                       ((b1v < myval) & ((b1v & 1u) ^ 1u)));
        int c0 = (int)(b0v > myval);
        int c1 = (int)(b1v == myval);
        newk = c0 & c1 & (ek ^ 1);
        newnk = ek;
      }
      kill |= newk;
      und &= (newk | newnk) ^ 1;
      u64 au = __ballot(und);
      if (lane == 0 && au) atomicOr(&misc[r & 3], 1u);
      if (tid == 0) misc[(r + 2) & 3] = 0u;              // recycle slot r+2
      __syncthreads();                                   // B2: reads done
      tUK[v1] = 0xFFFF;                                  // reset touched
      u32 anyu = misc[r & 3];
      __syncthreads();                                   // B3: reset visible
      if (anyu == 0u) break;
    }
    // ---- count & rank kills (pos order == tid order), apply, update ----
    u64 km = __ballot(kill);
    if (lane == 0) wred[wv] = (u32)__popcll(km);
    __syncthreads();                                     // B4
    if (tid == 0) {
      u32 run = 0;
      for (int w = 0; w < 16; ++w) { u32 t2 = wred[w]; wred[w] = run; run += t2; }
      wred[16] = run;
    }
    __syncthreads();                                     // B5
    u32 K = wred[16];
    if (kill) {
      u32 rank = wred[wv] + (u32)__popcll(km & ((1ull << lane) - 1ull));
      if (rank < (u32)remaining)
        atomicAnd(&alive[v1 >> 5], ~(1u << (v1 & 31)));
    }
    remaining -= (int)((K < (u32)remaining) ? K : (u32)remaining);
    if (tid < 4) misc[tid] = 0u;                         // clean for next batch
    __syncthreads();                                     // B6: applies visible
    pk = pkn;
  }
  for (int i = tid; i < 1600; i += 1024) gbits[i] = alive[i];
  if (tid == 0) out[E + V] = (float)(V - (needed - remaining));
}

// ---- K8: expand bit-mask to float outputs ----
__global__ __launch_bounds__(256) void expand_kernel(const u32* __restrict__ gbits,
                                                     float* __restrict__ out,
                                                     int V, int E) {
  int i = blockIdx.x * 256 + threadIdx.x;
  if (i < V) out[E + i] = ((gbits[i >> 5] >> (i & 31)) & 1) ? 1.0f : 0.0f;
}

extern "C" void kernel_launch(void* const* d_in, const int* in_sizes, int n_in,
                              void* d_out, int out_size, void* d_ws, size_t ws_size,
                              hipStream_t stream) {
  const float* image = (const float*)d_in[0];
  const float* vs    = (const float*)d_in[1];
  const int*   edges = (const int*)d_in[2];
  const int*   tgt   = (const int*)d_in[3];
  int V = in_sizes[1] / 2;                 // 50000
  int E = in_sizes[2] / 2;                 // 150000
  int Npad = ((E + 1023) / 1024) * 1024;   // 150528

  char* ws = (char*)d_ws;
  size_t o = 0;
  u64* keysA  = (u64*)(ws + o); o += (size_t)E * 8;
  u64* keysB  = (u64*)(ws + o); o += (size_t)E * 8;
  u64* pack   = (u64*)(ws + o); o += (size_t)Npad * 8;
  float* nrm  = (float*)(ws + o); o += (size_t)V * 4;
  u8*  bnd    = (u8*)(ws + o);  o += (size_t)E;
  o = (o + 255) & ~(size_t)255;
  u32* ghist  = (u32*)(ws + o); o += 16384 * 4;
  u32* starts = (u32*)(ws + o); o += 16385 * 4;
  u32* cursor = (u32*)(ws + o); o += 16384 * 4;
  u32* gbits  = (u32*)(ws + o); o += 6400;
  u32* gmm    = (u32*)(ws + o); o += 256;
  float* out = (float*)d_out;

  (void)hipMemsetAsync(ghist, 0, 16384 * 4, stream);
  (void)hipMemsetAsync(&gmm[0], 0xFF, 4, stream);   // min = 0xFFFFFFFF
  (void)hipMemsetAsync(&gmm[1], 0x00, 4, stream);   // max = 0

  int eb = (E + 255) / 256;
  vnorm_kernel<<<dim3((2 * V + 255) / 256), dim3(256), 0, stream>>>(image, nrm, V);
  edge_kernel<<<dim3(eb), dim3(256), 0, stream>>>(nrm, vs, edges, keysA, bnd, out, gmm, E);
  hist_kernel<<<dim3(eb), dim3(256), 0, stream>>>(keysA, gmm, ghist, E);
  scan16k_kernel<<<dim3(1), dim3(1024), 0, stream>>>(ghist, starts, cursor, E);
  scatter_kernel<<<dim3(eb), dim3(256), 0, stream>>>(keysA, gmm, cursor, keysB, E);
  bucketsort_kernel<<<dim3(4096), dim3(256), 0, stream>>>(keysB, starts, edges, bnd,
                                                          pack, E, V, Npad);
  batch_kernel<<<dim3(1), dim3(1024), 0, stream>>>(pack, tgt, out, gbits, V, E, Npad);
  expand_kernel<<<dim3((V + 255) / 256), dim3(256), 0, stream>>>(gbits, out, V, E);
}

// Round 13
// 237.092 us; speedup vs baseline: 2.4571x; 1.1007x over previous
//
#include <hip/hip_runtime.h>
#include <hip/hip_bf16.h>
#include <stdint.h>

typedef unsigned int u32;
typedef unsigned long long u64;
typedef unsigned char u8;
typedef unsigned short u16;

// ---------------------------------------------------------------------------
// Reduction order for n[v] = sum_f image[v,f]^2 bit-matches the XLA:CPU
// reference (H1 tree; vectorized form verified bit-exact, PASS R8-R12).
// ---------------------------------------------------------------------------

// ---- K1: per-vertex squared norm (2 lanes/vertex, float4 loads) ----
__global__ __launch_bounds__(256) void vnorm_kernel(const float* __restrict__ image,
                                                    float* __restrict__ nrm, int V) {
#pragma clang fp contract(off)
  int t = blockIdx.x * 256 + threadIdx.x;
  int v = t >> 1, h = t & 1;
  if (v >= V) return;
  const float4* r4 = (const float4*)(image + (size_t)v * 128) + h;
  float4 a, x;
  x = r4[0];
  a.x = x.x * x.x; a.y = x.y * x.y; a.z = x.z * x.z; a.w = x.w * x.w;
#pragma unroll
  for (int i = 1; i < 16; ++i) {
    x = r4[i * 2];
    a.x = a.x + x.x * x.x; a.y = a.y + x.y * x.y;
    a.z = a.z + x.z * x.z; a.w = a.w + x.w * x.w;
  }
  float bx = __shfl_xor(a.x, 1), by = __shfl_xor(a.y, 1);
  float bz = __shfl_xor(a.z, 1), bw = __shfl_xor(a.w, 1);
  a.x = a.x + bx; a.y = a.y + by; a.z = a.z + bz; a.w = a.w + bw;
  float r0 = a.x + a.z;
  float r1 = a.y + a.w;
  float s = r0 + r1;
  if (h == 0) nrm[v] = s;
}

// ---- K2: per-edge priority, key, boundary + global min/max ----
__global__ __launch_bounds__(256) void edge_kernel(const float* __restrict__ nrm,
                                                   const float* __restrict__ vs,
                                                   const int* __restrict__ edges,
                                                   u64* __restrict__ keysA,
                                                   u8* __restrict__ bnd,
                                                   float* __restrict__ out_sq,
                                                   u32* __restrict__ gmm, int E) {
#pragma clang fp contract(off)
  __shared__ u32 smn[4], smx[4];
  int tid = threadIdx.x;
  int e = blockIdx.x * 256 + tid;
  u32 mn = 0xFFFFFFFFu, mx = 0u;
  if (e < E) {
    int v0 = edges[e], v1 = edges[E + e];
    float sq = nrm[v0] + nrm[v1];
    out_sq[e] = sq;
    u32 sb = __float_as_uint(sq);
    keysA[e] = ((u64)sb << 32) | (u32)e;
    float ax = vs[2 * v0], ay = vs[2 * v0 + 1];
    float bx = vs[2 * v1], by = vs[2 * v1 + 1];
    const float lo = 0.01f, hi = 0.99f;
    bool b = (ax < lo) | (ax > hi) | (ay < lo) | (ay > hi)
           | (bx < lo) | (bx > hi) | (by < lo) | (by > hi);
    bnd[e] = b ? 1 : 0;
    mn = sb; mx = sb;
  }
  int lane = tid & 63, wv = tid >> 6;
#pragma unroll
  for (int d = 32; d >= 1; d >>= 1) {
    u32 a = __shfl_xor(mn, d); mn = (a < mn) ? a : mn;
    u32 b2 = __shfl_xor(mx, d); mx = (b2 > mx) ? b2 : mx;
  }
  if (lane == 0) { smn[wv] = mn; smx[wv] = mx; }
  __syncthreads();
  if (tid == 0) {
    u32 m = smn[0], M = smx[0];
#pragma unroll
    for (int w = 1; w < 4; ++w) {
      if (smn[w] < m) m = smn[w];
      if (smx[w] > M) M = smx[w];
    }
    atomicMin(&gmm[0], m);
    atomicMax(&gmm[1], M);
  }
}

__device__ inline u32 bucket_of(u32 sb, u32 minv, u32 range) {
  return (u32)(((u64)(sb - minv) << 14) / ((u64)range + 1ull));   // 16384 buckets
}

// ---- K3: bucket histogram ----
__global__ __launch_bounds__(256) void hist_kernel(const u64* __restrict__ keysA,
                                                   const u32* __restrict__ gmm,
                                                   u32* __restrict__ ghist, int E) {
  int e = blockIdx.x * 256 + threadIdx.x;
  if (e >= E) return;
  u32 minv = gmm[0], range = gmm[1] - minv;
  u32 b = bucket_of((u32)(keysA[e] >> 32), minv, range);
  atomicAdd(&ghist[b], 1u);
}

// ---- K4: scan of 16384 bucket counts ----
__global__ __launch_bounds__(1024) void scan16k_kernel(const u32* __restrict__ ghist,
                                                       u32* __restrict__ starts,
                                                       u32* __restrict__ cursor, int E) {
  __shared__ u32 wsum[16];
  int tid = threadIdx.x;
  int lane = tid & 63, wv = tid >> 6;
  u32 loc[16];
  u32 s = 0;
#pragma unroll
  for (int i = 0; i < 16; ++i) { loc[i] = ghist[tid * 16 + i]; s += loc[i]; }
  u32 inc = s;
#pragma unroll
  for (int d = 1; d < 64; d <<= 1) {
    u32 t = __shfl_up(inc, d);
    if (lane >= d) inc += t;
  }
  if (lane == 63) wsum[wv] = inc;
  __syncthreads();
  if (tid == 0) {
    u32 r = 0;
#pragma unroll
    for (int w = 0; w < 16; ++w) { u32 t = wsum[w]; wsum[w] = r; r += t; }
  }
  __syncthreads();
  u32 run = wsum[wv] + (inc - s);
#pragma unroll
  for (int i = 0; i < 16; ++i) {
    starts[tid * 16 + i] = run;
    cursor[tid * 16 + i] = run;
    run += loc[i];
  }
  if (tid == 0) starts[16384] = (u32)E;
}

// ---- K5: scatter keys into bucket slots ----
__global__ __launch_bounds__(256) void scatter_kernel(const u64* __restrict__ keysA,
                                                      const u32* __restrict__ gmm,
                                                      u32* __restrict__ cursor,
                                                      u64* __restrict__ keysB, int E) {
  int e = blockIdx.x * 256 + threadIdx.x;
  if (e >= E) return;
  u64 key = keysA[e];
  u32 minv = gmm[0], range = gmm[1] - minv;
  u32 b = bucket_of((u32)(key >> 32), minv, range);
  u32 pos = atomicAdd(&cursor[b], 1u);
  keysB[pos] = key;
}

// ---- K6: per-bucket 128-elem bitonic sort (1 wave/bucket) + pack write ----
__global__ __launch_bounds__(256) void bucketsort_kernel(const u64* __restrict__ keysB,
                                                         const u32* __restrict__ starts,
                                                         const int* __restrict__ edges,
                                                         const u8* __restrict__ bnd,
                                                         u64* __restrict__ pack,
                                                         int E, int V, int NpadB) {
  int tid = threadIdx.x;
  int lane = tid & 63;
  int w = blockIdx.x * 4 + (tid >> 6);           // bucket id
  u32 start = starts[w];
  int cnt = (int)(starts[w + 1] - start);
  if (cnt > 128) cnt = 128;                      // safety clamp (P ~ 0)
  u64 k0 = (lane < cnt) ? keysB[start + lane] : ~0ull;
  u64 k1 = (64 + lane < cnt) ? keysB[start + 64 + lane] : ~0ull;
  int idx0 = lane * 2, idx1 = lane * 2 + 1;
#pragma unroll
  for (int k = 2; k <= 128; k <<= 1) {
#pragma unroll
    for (int j = 64; j >= 1; j >>= 1) {
      if (j > k / 2) continue;
      if (j >= 2) {
        int lj = j >> 1;
        u64 p0 = __shfl_xor(k0, lj);
        u64 p1 = __shfl_xor(k1, lj);
        bool keepMin0 = (((idx0 & j) == 0) == ((idx0 & k) == 0));
        k0 = keepMin0 ? (k0 < p0 ? k0 : p0) : (k0 > p0 ? k0 : p0);
        k1 = keepMin0 ? (k1 < p1 ? k1 : p1) : (k1 > p1 ? k1 : p1);
      } else {
        bool up = ((idx0 & k) == 0);
        u64 mn = (k0 < k1) ? k0 : k1;
        u64 mx = (k0 < k1) ? k1 : k0;
        k0 = up ? mn : mx;
        k1 = up ? mx : mn;
      }
    }
  }
  if (idx0 < cnt) {
    u32 id = (u32)k0;
    int vv0 = edges[id], vv1 = edges[E + id];
    pack[start + idx0] = (u64)(u32)(vv0 | (vv1 << 16)) | ((u64)bnd[id] << 32);
  }
  if (idx1 < cnt) {
    u32 id = (u32)k1;
    int vv0 = edges[id], vv1 = edges[E + id];
    pack[start + idx1] = (u64)(u32)(vv0 | (vv1 << 16)) | ((u64)bnd[id] << 32);
  }
  // sentinel tail [E, NpadB): nb=1 (never kills), verts in [V, V+512)
  int g = blockIdx.x * 256 + tid;
  int i = E + g;
  if (i < NpadB) {
    u32 sv0 = (u32)V + (((u32)i & 255u) << 1);
    pack[i] = (u64)(sv0 | ((sv0 + 1) << 16)) | (1ull << 32);
  }
}

// ---- K7: exact greedy collapse, ordered 4096-edge batches + in-reg peel ---
// R12-verified decision logic, 4 slots/thread (position = s*1024 + tid):
//   tUK[v] = min over und|kill batch edges targeting v of (pos<<1)|isUnd.
//   und e: earlier KILL at v0|v1 -> NOKILL; no earlier und|kill at v0 AND
//   min at v1 -> KILL; else wait. Earliest undecided always decides.
// Threshold post-hoc per batch: rank kills by pos, apply first `remaining`.
// Also writes the float mask output directly (expand fused).
__device__ inline void lds_min_u16(u16* tarr, int idx, u16 val) {
  u32* w = (u32*)(tarr + (idx & ~1));
  int sh = (idx & 1) * 16;
  u32 old = *w;
  while (true) {
    u32 cur = (old >> sh) & 0xffffu;
    if ((u32)val >= cur) break;
    u32 nv = (old & ~(0xffffu << sh)) | ((u32)val << sh);
    u32 prev = atomicCAS(w, old, nv);
    if (prev == old) break;
    old = prev;
  }
}

#define NBAT 4096

__global__ __launch_bounds__(1024) void batch_kernel(const u64* __restrict__ pack,
                                                     const int* __restrict__ tgt,
                                                     float* __restrict__ out,
                                                     int V, int E, int NpadB) {
  __shared__ u16 tUK[50560];     // 101 KB; covers sentinel verts < V+512
  __shared__ u32 alive[1600];
  __shared__ u32 wred[65];
  __shared__ u32 misc[4];
  int tid = threadIdx.x;
  int lane = tid & 63, wv = tid >> 6;
  for (int i = tid; i < 1600; i += 1024) alive[i] = 0xFFFFFFFFu;
  for (int i = tid; i < 25280; i += 1024) ((u32*)tUK)[i] = 0xFFFFFFFFu;
  if (tid < 4) misc[tid] = 0u;
  int target = tgt[0];
  int needed = V - target; if (needed < 0) needed = 0;
  int remaining = needed;
  __syncthreads();
  int nbatch = NpadB / NBAT;
  u64 pk0 = pack[tid],        pk1 = pack[1024 + tid];
  u64 pk2 = pack[2048 + tid], pk3 = pack[3072 + tid];
  for (int b = 0; b < nbatch; ++b) {
    if (remaining <= 0) break;
    const u64* np = pack + (size_t)((b + 1 < nbatch) ? (b + 1) : b) * NBAT;
    u64 pn0 = np[tid],        pn1 = np[1024 + tid];
    u64 pn2 = np[2048 + tid], pn3 = np[3072 + tid];
    // ---- decode + init statuses from current alive ----
#define BDEC(S) \
    int v0##S = (int)(pk##S & 0xffff), w1##S = (int)((pk##S >> 16) & 0xffff); \
    int und##S, kill##S = 0; \
    { int nb_ = (int)((pk##S >> 32) & 1); \
      int a0 = (int)((alive[v0##S >> 5] >> (v0##S & 31)) & 1); \
      int a1 = (int)((alive[w1##S >> 5] >> (w1##S & 31)) & 1); \
      und##S = a0 & a1 & (nb_ ^ 1); } \
    u32 my##S = ((u32)(S * 1024 + tid) << 1) | 1u;
    BDEC(0) BDEC(1) BDEC(2) BDEC(3)
    for (int r = 0; r < 4200; ++r) {
#define BPOST(S) if (und##S | kill##S) \
      lds_min_u16(tUK, w1##S, (u16)((((u32)(S * 1024 + tid)) << 1) | (u32)und##S));
      BPOST(0) BPOST(1) BPOST(2) BPOST(3)
      __syncthreads();                                   // B1: posts visible
#define BDECIDE(S) \
      if (und##S) { \
        u32 b0v = (v0##S == w1##S) ? 0xFFFFu : (u32)tUK[v0##S]; \
        u32 b1v = (u32)tUK[w1##S]; \
        int ek = (int)(((b0v < my##S) & ((b0v & 1u) ^ 1u)) | \
                       ((b1v < my##S) & ((b1v & 1u) ^ 1u))); \
        int nk = (int)(b0v > my##S) & (int)(b1v == my##S) & (ek ^ 1); \
        kill##S |= nk; \
        und##S &= (nk | ek) ^ 1; \
      }
      BDECIDE(0) BDECIDE(1) BDECIDE(2) BDECIDE(3)
      u64 au = __ballot(und0 | und1 | und2 | und3);
      if (lane == 0 && au) atomicOr(&misc[r & 3], 1u);
      if (tid == 0) misc[(r + 2) & 3] = 0u;              // recycle slot r+2
      __syncthreads();                                   // B2: reads done
      tUK[w10] = 0xFFFF; tUK[w11] = 0xFFFF;              // reset touched
      tUK[w12] = 0xFFFF; tUK[w13] = 0xFFFF;
      u32 anyu = misc[r & 3];
      __syncthreads();                                   // B3: resets visible
      if (anyu == 0u) break;
    }
    // ---- rank kills in position order, apply first `remaining` ----
#define BRANK(S) { u64 km = __ballot(kill##S); \
      if (lane == 0) wred[S * 16 + wv] = (u32)__popcll(km); }
    BRANK(0) BRANK(1) BRANK(2) BRANK(3)
    if (tid < 4) misc[tid] = 0u;                         // clean for next batch
    __syncthreads();                                     // B4
    if (tid == 0) {
      u32 run = 0;
      for (int i = 0; i < 64; ++i) { u32 t2 = wred[i]; wred[i] = run; run += t2; }
      wred[64] = run;
    }
    __syncthreads();                                     // B5
    u32 K = wred[64];
#define BAPPLY(S) { u64 km = __ballot(kill##S); \
      if (kill##S) { \
        u32 rank = wred[S * 16 + wv] + (u32)__popcll(km & ((1ull << lane) - 1ull)); \
        if (rank < (u32)remaining) \
          atomicAnd(&alive[w1##S >> 5], ~(1u << (w1##S & 31))); } }
    BAPPLY(0) BAPPLY(1) BAPPLY(2) BAPPLY(3)
    remaining -= (int)((K < (u32)remaining) ? K : (u32)remaining);
    __syncthreads();                                     // B6: applies visible
    pk0 = pn0; pk1 = pn1; pk2 = pn2; pk3 = pn3;
  }
  // ---- fused expand: write float mask + count directly ----
  for (int i = tid; i < V; i += 1024)
    out[E + i] = ((alive[i >> 5] >> (i & 31)) & 1) ? 1.0f : 0.0f;
  if (tid == 0) out[E + V] = (float)(V - (needed - remaining));
}

extern "C" void kernel_launch(void* const* d_in, const int* in_sizes, int n_in,
                              void* d_out, int out_size, void* d_ws, size_t ws_size,
                              hipStream_t stream) {
  const float* image = (const float*)d_in[0];
  const float* vs    = (const float*)d_in[1];
  const int*   edges = (const int*)d_in[2];
  const int*   tgt   = (const int*)d_in[3];
  int V = in_sizes[1] / 2;                 // 50000
  int E = in_sizes[2] / 2;                 // 150000
  int NpadB = ((E + NBAT - 1) / NBAT) * NBAT;   // 151552 (37 x 4096)

  char* ws = (char*)d_ws;
  size_t o = 0;
  u64* keysA  = (u64*)(ws + o); o += (size_t)E * 8;
  u64* keysB  = (u64*)(ws + o); o += (size_t)E * 8;
  u64* pack   = (u64*)(ws + o); o += (size_t)NpadB * 8;
  float* nrm  = (float*)(ws + o); o += (size_t)V * 4;
  u8*  bnd    = (u8*)(ws + o);  o += (size_t)E;
  o = (o + 255) & ~(size_t)255;
  u32* ghist  = (u32*)(ws + o); o += 16384 * 4;
  u32* starts = (u32*)(ws + o); o += 16385 * 4;
  u32* cursor = (u32*)(ws + o); o += 16384 * 4;
  u32* gmm    = (u32*)(ws + o); o += 256;
  float* out = (float*)d_out;

  (void)hipMemsetAsync(ghist, 0, 16384 * 4, stream);
  (void)hipMemsetAsync(&gmm[0], 0xFF, 4, stream);   // min = 0xFFFFFFFF
  (void)hipMemsetAsync(&gmm[1], 0x00, 4, stream);   // max = 0

  int eb = (E + 255) / 256;
  vnorm_kernel<<<dim3((2 * V + 255) / 256), dim3(256), 0, stream>>>(image, nrm, V);
  edge_kernel<<<dim3(eb), dim3(256), 0, stream>>>(nrm, vs, edges, keysA, bnd, out, gmm, E);
  hist_kernel<<<dim3(eb), dim3(256), 0, stream>>>(keysA, gmm, ghist, E);
  scan16k_kernel<<<dim3(1), dim3(1024), 0, stream>>>(ghist, starts, cursor, E);
  scatter_kernel<<<dim3(eb), dim3(256), 0, stream>>>(keysA, gmm, cursor, keysB, E);
  bucketsort_kernel<<<dim3(4096), dim3(256), 0, stream>>>(keysB, starts, edges, bnd,
                                                          pack, E, V, NpadB);
  batch_kernel<<<dim3(1), dim3(1024), 0, stream>>>(pack, tgt, out, V, E, NpadB);
}